// Round 12
// baseline (161.880 us; speedup 1.0000x reference)
//
#include <hip/hip_runtime.h>
#include <hip/hip_bf16.h>
#include <math.h>

#define NH 8
#define HS 64
#define VOCAB 16384
#define QPH 2048                         // queries per head = b(4) * t(512)
#define NSLICE 32                        // vocab slices (512 rows each)
// fold 1/sqrt(512) * log2(e) into Q so the epilogue is p = exp2(score)
#define QSCALE (0.04419417382415922f * 1.4426950408889634f)

typedef __attribute__((ext_vector_type(8))) short bf16x8;
typedef __attribute__((ext_vector_type(4))) float f32x4;

static __device__ __forceinline__ unsigned short f2bfu(float f) {
    __hip_bfloat16 h = __float2bfloat16(f);
    unsigned short u;
    __builtin_memcpy(&u, &h, 2);
    return u;
}
static __device__ __forceinline__ short f2bfs(float f) {
    return (short)f2bfu(f);
}

static __device__ __forceinline__ float fexp2(float x) {
#if __has_builtin(__builtin_amdgcn_exp2f)
    return __builtin_amdgcn_exp2f(x);     // v_exp_f32 directly
#else
    return __expf(x * 0.6931471805599453f);
#endif
}

// ---------------- Kernel 1: qprep — Q = LayerNorm(enc(x)+PE) * QSCALE -> bf16 --------
__global__ void qprep(const float* __restrict__ x, const float* __restrict__ enc_w,
                      const float* __restrict__ enc_b, const float* __restrict__ ln_w,
                      const float* __restrict__ ln_b, unsigned short* __restrict__ qbf) {
    int row  = blockIdx.x * 4 + (threadIdx.x >> 6);  // n*2048 + q
    int h    = threadIdx.x & 63;
    int n = row >> 11;
    int q = row & 2047;
    int t = q & 511;
    float xv = x[q];
    int d = n * 64 + h;
    float h2  = (float)(h & ~1);
    float div = __expf(h2 * (-9.210340371976184f / 64.0f));
    float ang = (float)t * div;
    float pe  = (h & 1) ? __cosf(ang) : __sinf(ang);
    float v = xv * enc_w[d] + enc_b[d] + pe;
    float s = v;
    #pragma unroll
    for (int off = 1; off < 64; off <<= 1) s += __shfl_xor(s, off);
    float mu = s * (1.0f / 64.0f);
    float dd = v - mu;
    float s2 = dd * dd;
    #pragma unroll
    for (int off = 1; off < 64; off <<= 1) s2 += __shfl_xor(s2, off);
    float var = s2 * (1.0f / 64.0f);
    float y = dd * rsqrtf(var + 1e-5f) * ln_w[h] + ln_b[h];
    qbf[row * 64 + h] = f2bfu(y * QSCALE);
}

// ---------------- Kernel 2: attn — fused E-cast + g, trans-pipe-bound core -----------
// grid 1024 = qchunk(4)*256 + vslice(32)*8 + head(8); block 256 (4 waves).
// blockIdx % 8 == head: each XCD's share touches ONE head's E (4MB fp32 = L2).
// Wave w: 128 q (8 MFMA q-tiles, Q persistent 64 VGPR) x 512-row vocab slice,
// trip-16 K-loop (unroll disabled). Reads emb fp32 directly: converts to bf16
// frags in-register and computes g[v] = E[v,:].dec_w on the fly (fma + quad
// shfl-reduce + shfl broadcast) — eprep kernel deleted.
// CEILING MODEL (R3..R11): attn is transcendental-pipe bound (~88% busy at R9:
// 64 v_exp/iter vs 128 full-rate VALU -> VALUBusy 44% == trans/2). 268M exps
// ~= 54us chip floor; added cvt/fma/shfl (~150 cyc/iter) hides under 512 cyc
// of trans work.
// CODEGEN NOTES (hard-won):
//  - __launch_bounds__(256,3); tighter caps spill Q to scratch (R4: WRITE->1.5GB).
//  - K-loop must NOT fully unroll (R5: in-loop spill, FETCH 384MB). Guarded.
//  - q/wave sweet spot 128 (R6=32:143us, R3=64:82us, R9=128:60.6us, R10=256:
//    compiler refuses 128 VGPR of Q, rematerializes, no gain).
//  - watch VGPR (<160) and WRITE_SIZE (~4MB): else RA broke -> revert.
__global__ void __launch_bounds__(256, 3)
attn(const unsigned short* __restrict__ qbf, const float* __restrict__ emb,
     const float* __restrict__ dec_w, float2* __restrict__ part) {
    int tid  = threadIdx.x;
    int w    = tid >> 6;
    int lane = tid & 63;
    int quad = lane >> 4;
    int l15  = lane & 15;
    int head   = blockIdx.x & 7;
    int vslice = (blockIdx.x >> 3) & 31;   // 32 slices x 512 rows
    int qchunk = blockIdx.x >> 8;          // 4 chunks x 512 q
    int qbase  = (qchunk * 4 + w) * 128;   // 128 q per wave

    // persistent Q B-frags: B[k=hs][n=q], lane: n=l15, k = kf*32 + quad*8 + j
    const short* qp = (const short*)qbf + (size_t)(head * QPH + qbase) * HS;
    bf16x8 qf[8][2];
    #pragma unroll
    for (int qt = 0; qt < 8; ++qt) {
        const short* qrow = qp + (qt * 16 + l15) * HS + quad * 8;
        qf[qt][0] = *(const bf16x8*)(qrow);
        qf[qt][1] = *(const bf16x8*)(qrow + 32);
    }

    // dec_w slice for this lane's A-frag columns: cols quad*8+j (kf=0) and
    // 32+quad*8+j (kf=1)
    const float* dwh = dec_w + head * 64;
    float dwf[16];
    #pragma unroll
    for (int j = 0; j < 8; ++j) {
        dwf[j]     = dwh[quad * 8 + j];
        dwf[8 + j] = dwh[32 + quad * 8 + j];
    }

    const float* ep32 = emb + ((size_t)head * VOCAB + vslice * 512) * HS;

    float num[8] = {0.f, 0.f, 0.f, 0.f, 0.f, 0.f, 0.f, 0.f};
    float den[8] = {0.f, 0.f, 0.f, 0.f, 0.f, 0.f, 0.f, 0.f};
    const f32x4 z = {0.f, 0.f, 0.f, 0.f};

    #pragma clang loop unroll(disable)
    for (int it = 0; it < 16; ++it) {
        int vb = it * 32;
        // fp32 E rows for this lane: row0 = vb+l15, row1 = vb+16+l15
        const float* p0r = ep32 + (size_t)(vb + l15) * HS;
        const float* p1r = ep32 + (size_t)(vb + 16 + l15) * HS;
        f32x4 r0a = *(const f32x4*)(p0r + quad * 8);
        f32x4 r0b = *(const f32x4*)(p0r + quad * 8 + 4);
        f32x4 r0c = *(const f32x4*)(p0r + 32 + quad * 8);
        f32x4 r0d = *(const f32x4*)(p0r + 32 + quad * 8 + 4);
        f32x4 r1a = *(const f32x4*)(p1r + quad * 8);
        f32x4 r1b = *(const f32x4*)(p1r + quad * 8 + 4);
        f32x4 r1c = *(const f32x4*)(p1r + 32 + quad * 8);
        f32x4 r1d = *(const f32x4*)(p1r + 32 + quad * 8 + 4);

        // cast to MFMA A-frags (k = kf*32 + quad*8 + j)
        bf16x8 a00, a01, a10, a11;
        #pragma unroll
        for (int j = 0; j < 4; ++j) {
            a00[j] = f2bfs(r0a[j]); a00[4 + j] = f2bfs(r0b[j]);
            a01[j] = f2bfs(r0c[j]); a01[4 + j] = f2bfs(r0d[j]);
            a10[j] = f2bfs(r1a[j]); a10[4 + j] = f2bfs(r1b[j]);
            a11[j] = f2bfs(r1c[j]); a11[4 + j] = f2bfs(r1d[j]);
        }

        // g partials: lane covers 16 of 64 cols for its two rows
        float pr0 = 0.f, pr1 = 0.f;
        #pragma unroll
        for (int j = 0; j < 4; ++j) {
            pr0 += r0a[j] * dwf[j] + r0b[j] * dwf[4 + j]
                 + r0c[j] * dwf[8 + j] + r0d[j] * dwf[12 + j];
            pr1 += r1a[j] * dwf[j] + r1b[j] * dwf[4 + j]
                 + r1c[j] * dwf[8 + j] + r1d[j] * dwf[12 + j];
        }
        // reduce over the 4 quads (same l15): g0 = g[vb+l15], g1 = g[vb+16+l15]
        pr0 += __shfl_xor(pr0, 16); pr0 += __shfl_xor(pr0, 32);
        pr1 += __shfl_xor(pr1, 16); pr1 += __shfl_xor(pr1, 32);
        // broadcast to epilogue layout: lane needs g[vb + quad*4 + r] (+16);
        // value for row m lives (uniform over quads) in lanes with l15 == m;
        // fetch from own quad group: src = quad*16 + quad*4 + r = quad*20 + r
        f32x4 gv0, gv1;
        #pragma unroll
        for (int r = 0; r < 4; ++r) {
            gv0[r] = __shfl(pr0, quad * 20 + r);
            gv1[r] = __shfl(pr1, quad * 20 + r);
        }

        #pragma unroll
        for (int qt = 0; qt < 8; ++qt) {
            f32x4 acc0 = __builtin_amdgcn_mfma_f32_16x16x32_bf16(a00, qf[qt][0], z, 0, 0, 0);
            acc0       = __builtin_amdgcn_mfma_f32_16x16x32_bf16(a01, qf[qt][1], acc0, 0, 0, 0);
            f32x4 acc1 = __builtin_amdgcn_mfma_f32_16x16x32_bf16(a10, qf[qt][0], z, 0, 0, 0);
            acc1       = __builtin_amdgcn_mfma_f32_16x16x32_bf16(a11, qf[qt][1], acc1, 0, 0, 0);
            // D layout: col=l15=q, row=quad*4+r = v-within-16-tile
            #pragma unroll
            for (int r = 0; r < 4; ++r) {
                float p0 = fexp2(acc0[r]);
                float p1 = fexp2(acc1[r]);
                den[qt] += p0 + p1;
                num[qt] += p0 * gv0[r] + p1 * gv1[r];
            }
        }
    }

    // reduce across quads (same l15 = same q)
    #pragma unroll
    for (int qt = 0; qt < 8; ++qt) {
        num[qt] += __shfl_xor(num[qt], 16); num[qt] += __shfl_xor(num[qt], 32);
        den[qt] += __shfl_xor(den[qt], 16); den[qt] += __shfl_xor(den[qt], 32);
    }
    // slotted partials (no atomics): part[vslice][head][q]; quad commits 2 tiles
    #pragma unroll
    for (int j = 0; j < 2; ++j) {
        int qt = quad * 2 + j;
        int qg = qbase + qt * 16 + l15;
        part[((size_t)vslice * NH + head) * QPH + qg] = make_float2(num[qt], den[qt]);
    }
}

// ---------------- Kernel 3: fin — parallel over (n,q), LDS reduce over n -------------
__global__ void fin(const float2* __restrict__ part, const float* __restrict__ dec_b,
                    float* __restrict__ out) {
    __shared__ float red[8][32];
    int t  = threadIdx.x;
    int ql = t & 31;
    int n  = t >> 5;
    int q  = blockIdx.x * 32 + ql;
    float nv = 0.f, dv = 0.f;
    #pragma unroll 8
    for (int sl = 0; sl < NSLICE; ++sl) {
        float2 nd = part[((size_t)sl * NH + n) * QPH + q];
        nv += nd.x; dv += nd.y;
    }
    red[n][ql] = nv / dv;
    __syncthreads();
    if (t < 32) {
        float s = dec_b[0];
        #pragma unroll
        for (int m = 0; m < NH; ++m) s += red[m][t];
        out[q] = s;
    }
}

extern "C" void kernel_launch(void* const* d_in, const int* in_sizes, int n_in,
                              void* d_out, int out_size, void* d_ws, size_t ws_size,
                              hipStream_t stream) {
    const float* x     = (const float*)d_in[0];
    const float* emb   = (const float*)d_in[1];
    const float* enc_w = (const float*)d_in[2];
    const float* enc_b = (const float*)d_in[3];
    const float* ln_w  = (const float*)d_in[4];
    const float* ln_b  = (const float*)d_in[5];
    const float* dec_w = (const float*)d_in[6];
    const float* dec_b = (const float*)d_in[7];
    float* out = (float*)d_out;

    char* ws = (char*)d_ws;
    unsigned short* qbf  = (unsigned short*)(ws);             // 2 MB
    float2*         part = (float2*)(ws + 2097152);           // 4 MB (32*8*2048 float2)

    hipLaunchKernelGGL(qprep, dim3(4096), dim3(256), 0, stream, x, enc_w, enc_b, ln_w, ln_b, qbf);
    hipLaunchKernelGGL(attn,  dim3(1024), dim3(256), 0, stream, qbf, emb, dec_w, part);
    hipLaunchKernelGGL(fin,   dim3(64),   dim3(256), 0, stream, part, dec_b, out);
}

// Round 13
// 155.306 us; speedup vs baseline: 1.0423x; 1.0423x over previous
//
#include <hip/hip_runtime.h>
#include <hip/hip_bf16.h>
#include <math.h>

#define NH 8
#define HS 64
#define VOCAB 16384
#define QPH 2048                         // queries per head = b(4) * t(512)
#define NSLICE 64                        // vocab slices (256 rows each)
#define SROWS 256                        // rows per slice
#define LPAD 72                          // padded LDS row stride in shorts (144 B, 16B-aligned)
// fold 1/sqrt(512) * log2(e) into Q so the epilogue is p = exp2(score)
#define QSCALE (0.04419417382415922f * 1.4426950408889634f)

typedef __attribute__((ext_vector_type(8))) short bf16x8;
typedef __attribute__((ext_vector_type(4))) float f32x4;

static __device__ __forceinline__ unsigned short f2bfu(float f) {
    __hip_bfloat16 h = __float2bfloat16(f);
    unsigned short u;
    __builtin_memcpy(&u, &h, 2);
    return u;
}

static __device__ __forceinline__ float fexp2(float x) {
#if __has_builtin(__builtin_amdgcn_exp2f)
    return __builtin_amdgcn_exp2f(x);     // v_exp_f32 directly
#else
    return __expf(x * 0.6931471805599453f);
#endif
}

// ---------------- Kernel 1a: eprep — E -> bf16 cast + g[n][v] = E[n][v,:].dec_w ------
__global__ void eprep(const float* __restrict__ emb, const float* __restrict__ dec_w,
                      unsigned short* __restrict__ ebf, float* __restrict__ g) {
    int i4  = blockIdx.x * 256 + threadIdx.x;   // float4 index, total 2097152
    int row = i4 >> 4;                          // (n, v) row
    int c   = i4 & 15;
    int n   = row >> 14;
    f32x4 v = ((const f32x4*)emb)[i4];
    ushort4 u = make_ushort4(f2bfu(v.x), f2bfu(v.y), f2bfu(v.z), f2bfu(v.w));
    ((ushort4*)ebf)[i4] = u;
    const float* dw = dec_w + n * 64 + c * 4;
    float p = v.x * dw[0] + v.y * dw[1] + v.z * dw[2] + v.w * dw[3];
    p += __shfl_xor(p, 1); p += __shfl_xor(p, 2);
    p += __shfl_xor(p, 4); p += __shfl_xor(p, 8);
    if (c == 0) g[row] = p;
}

// ---------------- Kernel 1b: qprep — Q = LayerNorm(enc(x)+PE) * QSCALE -> bf16 -------
__global__ void qprep(const float* __restrict__ x, const float* __restrict__ enc_w,
                      const float* __restrict__ enc_b, const float* __restrict__ ln_w,
                      const float* __restrict__ ln_b, unsigned short* __restrict__ qbf) {
    int row  = blockIdx.x * 4 + (threadIdx.x >> 6);  // n*2048 + q
    int h    = threadIdx.x & 63;
    int n = row >> 11;
    int q = row & 2047;
    int t = q & 511;
    float xv = x[q];
    int d = n * 64 + h;
    float h2  = (float)(h & ~1);
    float div = __expf(h2 * (-9.210340371976184f / 64.0f));
    float ang = (float)t * div;
    float pe  = (h & 1) ? __cosf(ang) : __sinf(ang);
    float v = xv * enc_w[d] + enc_b[d] + pe;
    float s = v;
    #pragma unroll
    for (int off = 1; off < 64; off <<= 1) s += __shfl_xor(s, off);
    float mu = s * (1.0f / 64.0f);
    float dd = v - mu;
    float s2 = dd * dd;
    #pragma unroll
    for (int off = 1; off < 64; off <<= 1) s2 += __shfl_xor(s2, off);
    float var = s2 * (1.0f / 64.0f);
    float y = dd * rsqrtf(var + 1e-5f) * ln_w[h] + ln_b[h];
    qbf[row * 64 + h] = f2bfu(y * QSCALE);
}

// ---------------- Kernel 2: attn — LDS-staged E, single barrier ----------------------
// grid 2048 = qchunk(4)*512 + vslice(64)*8 + head(8); block 256 (4 waves).
// blockIdx % 8 == head: each XCD's share touches ONE head's E (2MB < 4MB L2).
// Block stages its 256-row E slice (bf16, padded stride 72) + g into 37 KB LDS
// with one coalesced pass + ONE barrier, then all 4 waves run the R9 compute
// body off ds_read_b128 (~120cyc vs ~200cyc L2, block-shared so per-q staging
// traffic drops 4x vs wave-private global loads). 4 blocks/CU (LDS-bound).
// Wave w: 128 q (8 MFMA q-tiles, Q persistent 64 VGPR) x slice, trip-8 K-loop.
// DIAGNOSIS (R12): VALU floor is only ~25us (exp chip-floor ~14us); R9's 61us
// was ~55% exposed VMEM latency. R2's LDS failure was per-iter barriers at
// 1 blk/CU, not LDS itself.
// CODEGEN NOTES (hard-won):
//  - launch_bounds (256,4): VGPR cap 128; tighter caps spill Q (R4: WRITE->1.5GB).
//  - K-loop must NOT fully unroll (R5: in-loop spill). Guarded.
//  - q/wave sweet spot 128 (R6=32:143us, R3=64:82us, R9=128:60.6us, R10=256:
//    compiler rematerializes Q, no gain).
//  - watch VGPR (<120) and WRITE_SIZE (~8MB incl part): else RA broke -> revert.
__global__ void __launch_bounds__(256, 4)
attn(const unsigned short* __restrict__ qbf, const unsigned short* __restrict__ ebf,
     const float* __restrict__ g, float2* __restrict__ part) {
    __shared__ short Es[SROWS * LPAD];   // 36864 B
    __shared__ float Gs[SROWS];          // 1024 B

    int tid  = threadIdx.x;
    int w    = tid >> 6;
    int lane = tid & 63;
    int quad = lane >> 4;
    int l15  = lane & 15;
    int head   = blockIdx.x & 7;
    int vslice = (blockIdx.x >> 3) & 63;   // 64 slices x 256 rows
    int qchunk = blockIdx.x >> 9;          // 4 chunks x 512 q
    int qbase  = (qchunk * 4 + w) * 128;   // 128 q per wave

    // ---- cooperative staging: 256 rows x 64 shorts, 8 rounds x 4KB ----
    const short* eg = (const short*)ebf + ((size_t)head * VOCAB + vslice * SROWS) * HS;
    const float* gp = g + head * VOCAB + vslice * SROWS;
    #pragma unroll
    for (int j = 0; j < 8; ++j) {
        int idx = j * 256 + tid;           // 8-short chunk id
        int row = idx >> 3;
        int c8  = idx & 7;
        bf16x8 v = *(const bf16x8*)(eg + row * HS + c8 * 8);
        *(bf16x8*)(&Es[row * LPAD + c8 * 8]) = v;
    }
    Gs[tid] = gp[tid];

    // persistent Q B-frags: B[k=hs][n=q], lane: n=l15, k = kf*32 + quad*8 + j
    const short* qp = (const short*)qbf + (size_t)(head * QPH + qbase) * HS;
    bf16x8 qf[8][2];
    #pragma unroll
    for (int qt = 0; qt < 8; ++qt) {
        const short* qrow = qp + (qt * 16 + l15) * HS + quad * 8;
        qf[qt][0] = *(const bf16x8*)(qrow);
        qf[qt][1] = *(const bf16x8*)(qrow + 32);
    }

    __syncthreads();   // the ONLY barrier

    float num[8] = {0.f, 0.f, 0.f, 0.f, 0.f, 0.f, 0.f, 0.f};
    float den[8] = {0.f, 0.f, 0.f, 0.f, 0.f, 0.f, 0.f, 0.f};
    const f32x4 z = {0.f, 0.f, 0.f, 0.f};

    #pragma clang loop unroll(disable)
    for (int it = 0; it < 8; ++it) {
        int vb = it * 32;
        // A-frags from LDS: A[m=v][k], lane: m=l15(+16), k=kf*32+quad*8+j
        const short* e0 = &Es[(vb + l15) * LPAD + quad * 8];
        const short* e1 = &Es[(vb + 16 + l15) * LPAD + quad * 8];
        bf16x8 a00 = *(const bf16x8*)(e0);
        bf16x8 a01 = *(const bf16x8*)(e0 + 32);
        bf16x8 a10 = *(const bf16x8*)(e1);
        bf16x8 a11 = *(const bf16x8*)(e1 + 32);
        f32x4 gv0 = *(const f32x4*)(&Gs[vb + quad * 4]);
        f32x4 gv1 = *(const f32x4*)(&Gs[vb + 16 + quad * 4]);
        #pragma unroll
        for (int qt = 0; qt < 8; ++qt) {
            f32x4 acc0 = __builtin_amdgcn_mfma_f32_16x16x32_bf16(a00, qf[qt][0], z, 0, 0, 0);
            acc0       = __builtin_amdgcn_mfma_f32_16x16x32_bf16(a01, qf[qt][1], acc0, 0, 0, 0);
            f32x4 acc1 = __builtin_amdgcn_mfma_f32_16x16x32_bf16(a10, qf[qt][0], z, 0, 0, 0);
            acc1       = __builtin_amdgcn_mfma_f32_16x16x32_bf16(a11, qf[qt][1], acc1, 0, 0, 0);
            // D layout: col=l15=q, row=quad*4+r = v-within-16-tile
            #pragma unroll
            for (int r = 0; r < 4; ++r) {
                float p0 = fexp2(acc0[r]);
                float p1 = fexp2(acc1[r]);
                den[qt] += p0 + p1;
                num[qt] += p0 * gv0[r] + p1 * gv1[r];
            }
        }
    }

    // reduce across quads (same l15 = same q)
    #pragma unroll
    for (int qt = 0; qt < 8; ++qt) {
        num[qt] += __shfl_xor(num[qt], 16); num[qt] += __shfl_xor(num[qt], 32);
        den[qt] += __shfl_xor(den[qt], 16); den[qt] += __shfl_xor(den[qt], 32);
    }
    // slotted partials (no atomics): part[vslice][head][q]; quad commits 2 tiles
    #pragma unroll
    for (int j = 0; j < 2; ++j) {
        int qt = quad * 2 + j;
        int qg = qbase + qt * 16 + l15;
        part[((size_t)vslice * NH + head) * QPH + qg] = make_float2(num[qt], den[qt]);
    }
}

// ---------------- Kernel 3: fin — parallel over (n,q), LDS reduce over n -------------
__global__ void fin(const float2* __restrict__ part, const float* __restrict__ dec_b,
                    float* __restrict__ out) {
    __shared__ float red[8][32];
    int t  = threadIdx.x;
    int ql = t & 31;
    int n  = t >> 5;
    int q  = blockIdx.x * 32 + ql;
    float nv = 0.f, dv = 0.f;
    #pragma unroll 8
    for (int sl = 0; sl < NSLICE; ++sl) {
        float2 nd = part[((size_t)sl * NH + n) * QPH + q];
        nv += nd.x; dv += nd.y;
    }
    red[n][ql] = nv / dv;
    __syncthreads();
    if (t < 32) {
        float s = dec_b[0];
        #pragma unroll
        for (int m = 0; m < NH; ++m) s += red[m][t];
        out[q] = s;
    }
}

extern "C" void kernel_launch(void* const* d_in, const int* in_sizes, int n_in,
                              void* d_out, int out_size, void* d_ws, size_t ws_size,
                              hipStream_t stream) {
    const float* x     = (const float*)d_in[0];
    const float* emb   = (const float*)d_in[1];
    const float* enc_w = (const float*)d_in[2];
    const float* enc_b = (const float*)d_in[3];
    const float* ln_w  = (const float*)d_in[4];
    const float* ln_b  = (const float*)d_in[5];
    const float* dec_w = (const float*)d_in[6];
    const float* dec_b = (const float*)d_in[7];
    float* out = (float*)d_out;

    char* ws = (char*)d_ws;
    unsigned short* qbf  = (unsigned short*)(ws);                        // 2 MB
    unsigned short* ebf  = (unsigned short*)(ws + 2097152);              // 16 MB
    float*          g    = (float*)(ws + 2097152 + 16777216);            // 512 KB
    float2*         part = (float2*)(ws + 2097152 + 16777216 + 524288);  // 8 MB (64*8*2048 float2)

    hipLaunchKernelGGL(eprep, dim3(8192), dim3(256), 0, stream, emb, dec_w, ebf, g);
    hipLaunchKernelGGL(qprep, dim3(4096), dim3(256), 0, stream, x, enc_w, enc_b, ln_w, ln_b, qbf);
    hipLaunchKernelGGL(attn,  dim3(2048), dim3(256), 0, stream, qbf, ebf, g, part);
    hipLaunchKernelGGL(fin,   dim3(64),   dim3(256), 0, stream, part, dec_b, out);
}

// Round 14
// 152.999 us; speedup vs baseline: 1.0580x; 1.0151x over previous
//
#include <hip/hip_runtime.h>
#include <hip/hip_bf16.h>
#include <math.h>

#define NH 8
#define HS 64
#define VOCAB 16384
#define QPH 2048                         // queries per head = b(4) * t(512)
#define NSLICE 32                        // vocab slices (512 rows each)
// fold 1/sqrt(512) * log2(e) into Q so the epilogue is p = exp2(score)
#define QSCALE (0.04419417382415922f * 1.4426950408889634f)

typedef __attribute__((ext_vector_type(8))) short bf16x8;
typedef __attribute__((ext_vector_type(4))) float f32x4;
typedef __attribute__((ext_vector_type(2))) float f32x2;

static __device__ __forceinline__ unsigned short f2bfu(float f) {
    __hip_bfloat16 h = __float2bfloat16(f);
    unsigned short u;
    __builtin_memcpy(&u, &h, 2);
    return u;
}

static __device__ __forceinline__ float fexp2(float x) {
#if __has_builtin(__builtin_amdgcn_exp2f)
    return __builtin_amdgcn_exp2f(x);     // v_exp_f32 directly
#else
    return __expf(x * 0.6931471805599453f);
#endif
}

// ---------------- Kernel 1a: eprep — E -> bf16 cast + g[n][v] = E[n][v,:].dec_w ------
__global__ void eprep(const float* __restrict__ emb, const float* __restrict__ dec_w,
                      unsigned short* __restrict__ ebf, float* __restrict__ g) {
    int i4  = blockIdx.x * 256 + threadIdx.x;   // float4 index, total 2097152
    int row = i4 >> 4;                          // (n, v) row
    int c   = i4 & 15;
    int n   = row >> 14;
    f32x4 v = ((const f32x4*)emb)[i4];
    ushort4 u = make_ushort4(f2bfu(v.x), f2bfu(v.y), f2bfu(v.z), f2bfu(v.w));
    ((ushort4*)ebf)[i4] = u;
    const float* dw = dec_w + n * 64 + c * 4;
    float p = v.x * dw[0] + v.y * dw[1] + v.z * dw[2] + v.w * dw[3];
    p += __shfl_xor(p, 1); p += __shfl_xor(p, 2);
    p += __shfl_xor(p, 4); p += __shfl_xor(p, 8);
    if (c == 0) g[row] = p;
}

// ---------------- Kernel 1b: qprep — Q = LayerNorm(enc(x)+PE) * QSCALE -> bf16 -------
__global__ void qprep(const float* __restrict__ x, const float* __restrict__ enc_w,
                      const float* __restrict__ enc_b, const float* __restrict__ ln_w,
                      const float* __restrict__ ln_b, unsigned short* __restrict__ qbf) {
    int row  = blockIdx.x * 4 + (threadIdx.x >> 6);  // n*2048 + q
    int h    = threadIdx.x & 63;
    int n = row >> 11;
    int q = row & 2047;
    int t = q & 511;
    float xv = x[q];
    int d = n * 64 + h;
    float h2  = (float)(h & ~1);
    float div = __expf(h2 * (-9.210340371976184f / 64.0f));
    float ang = (float)t * div;
    float pe  = (h & 1) ? __cosf(ang) : __sinf(ang);
    float v = xv * enc_w[d] + enc_b[d] + pe;
    float s = v;
    #pragma unroll
    for (int off = 1; off < 64; off <<= 1) s += __shfl_xor(s, off);
    float mu = s * (1.0f / 64.0f);
    float dd = v - mu;
    float s2 = dd * dd;
    #pragma unroll
    for (int off = 1; off < 64; off <<= 1) s2 += __shfl_xor(s2, off);
    float var = s2 * (1.0f / 64.0f);
    float y = dd * rsqrtf(var + 1e-5f) * ln_w[h] + ln_b[h];
    qbf[row * 64 + h] = f2bfu(y * QSCALE);
}

// ---------------- Kernel 2: attn — R11 config + packed-fp32 epilogue -----------------
// grid 1024 = qchunk(4)*256 + vslice(32)*8 + head(8); block 256 (4 waves).
// blockIdx % 8 == head: each XCD's share touches ONE head's E (2MB < 4MB L2).
// Wave w: 128 q (8 MFMA q-tiles, Q persistent 64 VGPR) x 512-row vocab slice,
// trip-16 K-loop (unroll disabled).
// MODEL (R9/R12/R13): attn is ISSUE-bound on the inner-loop instruction stream
// (~250 instrs/iter; LDS vs global staging neutral at 4 waves/SIMD resident;
// added VALU shows up ~1:1 in wall — R12). This round: epilogue 4 scalar ops
// per exp-pair -> 2 packed (v_pk_fma_f32 / v_pk_add_f32) on float2
// accumulators, also splitting the den/num dependency chains.
// CODEGEN NOTES (hard-won):
//  - __launch_bounds__(256,3); tighter caps spill Q to scratch (R4: WRITE->1.5GB).
//  - K-loop must NOT fully unroll (R5: in-loop spill, FETCH 384MB). Guarded.
//  - q/wave sweet spot 128 (R6=32:143us, R3=64:82us, R9=128:60.6us, R10=256:
//    compiler rematerializes Q, no gain).
//  - watch VGPR (<120) and WRITE_SIZE (~4MB): else RA broke -> revert.
__global__ void __launch_bounds__(256, 3)
attn(const unsigned short* __restrict__ qbf, const unsigned short* __restrict__ ebf,
     const float* __restrict__ g, float2* __restrict__ part) {
    int tid  = threadIdx.x;
    int w    = tid >> 6;
    int lane = tid & 63;
    int quad = lane >> 4;
    int l15  = lane & 15;
    int head   = blockIdx.x & 7;
    int vslice = (blockIdx.x >> 3) & 31;   // 32 slices x 512 rows
    int qchunk = blockIdx.x >> 8;          // 4 chunks x 512 q
    int qbase  = (qchunk * 4 + w) * 128;   // 128 q per wave

    // persistent Q B-frags: B[k=hs][n=q], lane: n=l15, k = kf*32 + quad*8 + j
    const short* qp = (const short*)qbf + (size_t)(head * QPH + qbase) * HS;
    bf16x8 qf[8][2];
    #pragma unroll
    for (int qt = 0; qt < 8; ++qt) {
        const short* qrow = qp + (qt * 16 + l15) * HS + quad * 8;
        qf[qt][0] = *(const bf16x8*)(qrow);
        qf[qt][1] = *(const bf16x8*)(qrow + 32);
    }

    const short* ep = (const short*)ebf + ((size_t)head * VOCAB + vslice * 512) * HS;
    const float* gp = g + head * VOCAB + vslice * 512;

    // packed accumulators: sum2 = {den_a, den_b}, wsum2 = {num_a, num_b}
    f32x2 sum2[8], wsum2[8];
    #pragma unroll
    for (int qt = 0; qt < 8; ++qt) {
        sum2[qt]  = (f32x2){0.f, 0.f};
        wsum2[qt] = (f32x2){0.f, 0.f};
    }
    const f32x4 z = {0.f, 0.f, 0.f, 0.f};

    #pragma clang loop unroll(disable)
    for (int it = 0; it < 16; ++it) {
        int vb = it * 32;
        // A-frags direct from global (L2): A[m=v][k], lane: m=l15(+16), k=kf*32+quad*8+j
        const short* e0 = ep + (size_t)(vb + l15) * HS + quad * 8;
        const short* e1 = ep + (size_t)(vb + 16 + l15) * HS + quad * 8;
        bf16x8 a00 = *(const bf16x8*)(e0);
        bf16x8 a01 = *(const bf16x8*)(e0 + 32);
        bf16x8 a10 = *(const bf16x8*)(e1);
        bf16x8 a11 = *(const bf16x8*)(e1 + 32);
        f32x4 gv0 = *(const f32x4*)(gp + vb + quad * 4);
        f32x4 gv1 = *(const f32x4*)(gp + vb + 16 + quad * 4);
        // packed g pairs, shared across all 8 q-tiles
        f32x2 gg[4];
        #pragma unroll
        for (int r = 0; r < 4; ++r) gg[r] = (f32x2){gv0[r], gv1[r]};

        #pragma unroll
        for (int qt = 0; qt < 8; ++qt) {
            f32x4 acc0 = __builtin_amdgcn_mfma_f32_16x16x32_bf16(a00, qf[qt][0], z, 0, 0, 0);
            acc0       = __builtin_amdgcn_mfma_f32_16x16x32_bf16(a01, qf[qt][1], acc0, 0, 0, 0);
            f32x4 acc1 = __builtin_amdgcn_mfma_f32_16x16x32_bf16(a10, qf[qt][0], z, 0, 0, 0);
            acc1       = __builtin_amdgcn_mfma_f32_16x16x32_bf16(a11, qf[qt][1], acc1, 0, 0, 0);
            // D layout: col=l15=q, row=quad*4+r = v-within-16-tile
            #pragma unroll
            for (int r = 0; r < 4; ++r) {
                f32x2 pp = (f32x2){fexp2(acc0[r]), fexp2(acc1[r])};
                wsum2[qt] += pp * gg[r];   // v_pk_fma_f32
                sum2[qt]  += pp;           // v_pk_add_f32
            }
        }
    }

    // collapse packed halves, then reduce across quads (same l15 = same q)
    float num[8], den[8];
    #pragma unroll
    for (int qt = 0; qt < 8; ++qt) {
        num[qt] = wsum2[qt].x + wsum2[qt].y;
        den[qt] = sum2[qt].x + sum2[qt].y;
        num[qt] += __shfl_xor(num[qt], 16); num[qt] += __shfl_xor(num[qt], 32);
        den[qt] += __shfl_xor(den[qt], 16); den[qt] += __shfl_xor(den[qt], 32);
    }
    // slotted partials (no atomics): part[vslice][head][q]; quad commits 2 tiles
    #pragma unroll
    for (int j = 0; j < 2; ++j) {
        int qt = quad * 2 + j;
        int qg = qbase + qt * 16 + l15;
        part[((size_t)vslice * NH + head) * QPH + qg] = make_float2(num[qt], den[qt]);
    }
}

// ---------------- Kernel 3: fin — parallel over (n,q), LDS reduce over n -------------
__global__ void fin(const float2* __restrict__ part, const float* __restrict__ dec_b,
                    float* __restrict__ out) {
    __shared__ float red[8][32];
    int t  = threadIdx.x;
    int ql = t & 31;
    int n  = t >> 5;
    int q  = blockIdx.x * 32 + ql;
    float nv = 0.f, dv = 0.f;
    #pragma unroll 8
    for (int sl = 0; sl < NSLICE; ++sl) {
        float2 nd = part[((size_t)sl * NH + n) * QPH + q];
        nv += nd.x; dv += nd.y;
    }
    red[n][ql] = nv / dv;
    __syncthreads();
    if (t < 32) {
        float s = dec_b[0];
        #pragma unroll
        for (int m = 0; m < NH; ++m) s += red[m][t];
        out[q] = s;
    }
}

extern "C" void kernel_launch(void* const* d_in, const int* in_sizes, int n_in,
                              void* d_out, int out_size, void* d_ws, size_t ws_size,
                              hipStream_t stream) {
    const float* x     = (const float*)d_in[0];
    const float* emb   = (const float*)d_in[1];
    const float* enc_w = (const float*)d_in[2];
    const float* enc_b = (const float*)d_in[3];
    const float* ln_w  = (const float*)d_in[4];
    const float* ln_b  = (const float*)d_in[5];
    const float* dec_w = (const float*)d_in[6];
    const float* dec_b = (const float*)d_in[7];
    float* out = (float*)d_out;

    char* ws = (char*)d_ws;
    unsigned short* qbf  = (unsigned short*)(ws);                        // 2 MB
    unsigned short* ebf  = (unsigned short*)(ws + 2097152);              // 16 MB
    float*          g    = (float*)(ws + 2097152 + 16777216);            // 512 KB
    float2*         part = (float2*)(ws + 2097152 + 16777216 + 524288);  // 4 MB (32*8*2048 float2)

    hipLaunchKernelGGL(eprep, dim3(8192), dim3(256), 0, stream, emb, dec_w, ebf, g);
    hipLaunchKernelGGL(qprep, dim3(4096), dim3(256), 0, stream, x, enc_w, enc_b, ln_w, ln_b, qbf);
    hipLaunchKernelGGL(attn,  dim3(1024), dim3(256), 0, stream, qbf, ebf, g, part);
    hipLaunchKernelGGL(fin,   dim3(64),   dim3(256), 0, stream, part, dec_b, out);
}